// Round 3
// baseline (1899.548 us; speedup 1.0000x reference)
//
#include <hip/hip_runtime.h>
#include <hip/hip_bf16.h>

// Problem constants (from reference)
#define NU 100000
#define NI 50000
#define NE 1000000
#define NP 500000
// D_IN = D_HID = 128, D_OUT = 64

// ---------------- CSR build ----------------

__global__ void hist_kernel(const int* __restrict__ dst, int* __restrict__ deg, int E) {
    int e = blockIdx.x * blockDim.x + threadIdx.x;
    if (e < E) atomicAdd(&deg[dst[e]], 1);
}

__global__ void scan_local_kernel(const int* __restrict__ in, int* __restrict__ out,
                                  int* __restrict__ bsum, int n) {
    __shared__ int s[1024];
    int i = blockIdx.x * 1024 + threadIdx.x;
    int v = (i < n) ? in[i] : 0;
    s[threadIdx.x] = v;
    __syncthreads();
    for (int off = 1; off < 1024; off <<= 1) {
        int t = (threadIdx.x >= off) ? s[threadIdx.x - off] : 0;
        __syncthreads();
        s[threadIdx.x] += t;
        __syncthreads();
    }
    if (i < n) out[i] = s[threadIdx.x] - v;   // exclusive within block
    if (threadIdx.x == 1023) bsum[blockIdx.x] = s[1023];
}

__global__ void scan_bsum_kernel(int* bsum, int nb) {
    __shared__ int s[1024];
    int v = (threadIdx.x < nb) ? bsum[threadIdx.x] : 0;
    s[threadIdx.x] = v;
    __syncthreads();
    for (int off = 1; off < 1024; off <<= 1) {
        int t = (threadIdx.x >= off) ? s[threadIdx.x - off] : 0;
        __syncthreads();
        s[threadIdx.x] += t;
        __syncthreads();
    }
    if (threadIdx.x < nb) bsum[threadIdx.x] = s[threadIdx.x] - v;  // exclusive
}

__global__ void scan_finalize_kernel(int* __restrict__ rs, const int* __restrict__ bsum,
                                     int* __restrict__ cursor, int n, int E) {
    int i = blockIdx.x * 1024 + threadIdx.x;
    if (i < n) {
        int v = rs[i] + bsum[blockIdx.x];
        rs[i] = v;
        cursor[i] = v;
    }
    if (i == 0) rs[n] = E;
}

__global__ void fill_kernel(const int* __restrict__ src, const int* __restrict__ dst,
                            int* cursor, int* __restrict__ csr, int E) {
    int e = blockIdx.x * blockDim.x + threadIdx.x;
    if (e < E) {
        int p = atomicAdd(&cursor[dst[e]], 1);
        csr[p] = src[e];
    }
}

// ---------------- mean aggregation (CSR, atomic-free) ----------------
// 2 dst nodes per 256-thread block; thread j owns feature dim j (128 dims).
__global__ __launch_bounds__(256) void agg_kernel(const float* __restrict__ hsrc,
                                                  const int* __restrict__ rs,
                                                  const int* __restrict__ csr,
                                                  float* __restrict__ out, int T) {
    int t = blockIdx.x * 2 + (threadIdx.x >> 7);
    int j = threadIdx.x & 127;
    if (t >= T) return;
    int e0 = rs[t], e1 = rs[t + 1];
    float acc = 0.f;
    for (int e = e0; e < e1; ++e) {
        int s = csr[e];
        acc += hsrc[(size_t)s * 128 + j];
    }
    float inv = (e1 > e0) ? 1.f / (float)(e1 - e0) : 0.f;
    out[(size_t)t * 128 + j] = acc * inv;
}

// ---------------- conv: z = hn@Wn + bn + hd@Ws + bs; relu; row L2-norm ----------------
// Tile: 32 rows x DOUT cols per 256-thread block. A = [hn | hd] staged in LDS (K=256).
template <int DOUT>
__global__ __launch_bounds__(256) void conv_kernel(const float* __restrict__ hn,
                                                   const float* __restrict__ hd,
                                                   const float* __restrict__ Wn,
                                                   const float* __restrict__ bn,
                                                   const float* __restrict__ Ws,
                                                   const float* __restrict__ bs,
                                                   float* __restrict__ out, int T) {
    constexpr int TM = 32;
    constexpr int GROUP = DOUT / 4;            // threads cooperating on one row set
    constexpr int RPT = (TM * GROUP) / 256;    // rows per thread (4 for 128, 2 for 64)
    __shared__ float A[TM][264];               // 264: 16B-aligned rows, bank-spread

    const int tid = threadIdx.x;
    const int t0 = blockIdx.x * TM;

    // stage [hn | hd] tile: 32 rows x 256 floats = 2048 float4, 8 per thread
    #pragma unroll
    for (int i = 0; i < 8; ++i) {
        int lin = i * 256 + tid;
        int row = lin >> 6;
        int q   = lin & 63;
        int t   = t0 + row;
        float4 v = {0.f, 0.f, 0.f, 0.f};
        if (t < T) {
            v = (q < 32) ? *(const float4*)&hn[(size_t)t * 128 + (q << 2)]
                         : *(const float4*)&hd[(size_t)t * 128 + ((q - 32) << 2)];
        }
        *(float4*)&A[row][q << 2] = v;
    }
    __syncthreads();

    const int cg = tid % GROUP, rg = tid / GROUP;
    const int c0 = cg * 4, r0 = rg * RPT;

    float acc[RPT][4] = {};
    #pragma unroll
    for (int half = 0; half < 2; ++half) {
        const float* __restrict__ W = half ? Ws : Wn;
        const int kb = half * 128;
        for (int k = 0; k < 128; k += 4) {
            float4 w0 = *(const float4*)&W[(size_t)(k + 0) * DOUT + c0];
            float4 w1 = *(const float4*)&W[(size_t)(k + 1) * DOUT + c0];
            float4 w2 = *(const float4*)&W[(size_t)(k + 2) * DOUT + c0];
            float4 w3 = *(const float4*)&W[(size_t)(k + 3) * DOUT + c0];
            #pragma unroll
            for (int r = 0; r < RPT; ++r) {
                float4 a = *(const float4*)&A[r0 + r][kb + k];
                acc[r][0] = fmaf(a.x, w0.x, acc[r][0]);
                acc[r][1] = fmaf(a.x, w0.y, acc[r][1]);
                acc[r][2] = fmaf(a.x, w0.z, acc[r][2]);
                acc[r][3] = fmaf(a.x, w0.w, acc[r][3]);
                acc[r][0] = fmaf(a.y, w1.x, acc[r][0]);
                acc[r][1] = fmaf(a.y, w1.y, acc[r][1]);
                acc[r][2] = fmaf(a.y, w1.z, acc[r][2]);
                acc[r][3] = fmaf(a.y, w1.w, acc[r][3]);
                acc[r][0] = fmaf(a.z, w2.x, acc[r][0]);
                acc[r][1] = fmaf(a.z, w2.y, acc[r][1]);
                acc[r][2] = fmaf(a.z, w2.z, acc[r][2]);
                acc[r][3] = fmaf(a.z, w2.w, acc[r][3]);
                acc[r][0] = fmaf(a.w, w3.x, acc[r][0]);
                acc[r][1] = fmaf(a.w, w3.y, acc[r][1]);
                acc[r][2] = fmaf(a.w, w3.z, acc[r][2]);
                acc[r][3] = fmaf(a.w, w3.w, acc[r][3]);
            }
        }
    }

    float bias[4];
    #pragma unroll
    for (int c = 0; c < 4; ++c) bias[c] = bn[c0 + c] + bs[c0 + c];

    #pragma unroll
    for (int r = 0; r < RPT; ++r) {
        float n2 = 0.f;
        #pragma unroll
        for (int c = 0; c < 4; ++c) {
            float z = fmaxf(acc[r][c] + bias[c], 0.f);
            acc[r][c] = z;
            n2 = fmaf(z, z, n2);
        }
        #pragma unroll
        for (int m = 1; m < GROUP; m <<= 1) n2 += __shfl_xor(n2, m);
        float inv = 1.f / fmaxf(sqrtf(n2), 1e-12f);
        int t = t0 + r0 + r;
        if (t < T) {
            float4 o = {acc[r][0] * inv, acc[r][1] * inv, acc[r][2] * inv, acc[r][3] * inv};
            *(float4*)&out[(size_t)t * DOUT + c0] = o;
        }
    }
}

// ---------------- cosine scores ----------------
// 16 lanes per pair (16 x float4 = 64 dims)
__global__ __launch_bounds__(256) void score_kernel(const float* __restrict__ hu,
                                                    const float* __restrict__ hi,
                                                    const int* __restrict__ pu,
                                                    const int* __restrict__ pi,
                                                    float* __restrict__ out, int P) {
    int g = threadIdx.x >> 4, l = threadIdx.x & 15;
    int p = blockIdx.x * 16 + g;
    if (p >= P) return;
    int u = pu[p], it = pi[p];
    float4 a = *(const float4*)&hu[(size_t)u * 64 + (l << 2)];
    float4 b = *(const float4*)&hi[(size_t)it * 64 + (l << 2)];
    float d  = a.x * b.x + a.y * b.y + a.z * b.z + a.w * b.w;
    float na = a.x * a.x + a.y * a.y + a.z * a.z + a.w * a.w;
    float nb = b.x * b.x + b.y * b.y + b.z * b.z + b.w * b.w;
    #pragma unroll
    for (int m = 1; m < 16; m <<= 1) {
        d  += __shfl_xor(d, m);
        na += __shfl_xor(na, m);
        nb += __shfl_xor(nb, m);
    }
    if (l == 0) out[p] = d / (fmaxf(sqrtf(na), 1e-12f) * fmaxf(sqrtf(nb), 1e-12f));
}

// ---------------- host ----------------

extern "C" void kernel_launch(void* const* d_in, const int* in_sizes, int n_in,
                              void* d_out, int out_size, void* d_ws, size_t ws_size,
                              hipStream_t stream) {
    const float* h_user = (const float*)d_in[0];
    const float* h_item = (const float*)d_in[1];
    const float* Wn01   = (const float*)d_in[2];
    const float* bn01   = (const float*)d_in[3];
    const float* Ws01   = (const float*)d_in[4];
    const float* bs01   = (const float*)d_in[5];
    const float* Wn2    = (const float*)d_in[6];
    const float* bn2    = (const float*)d_in[7];
    const float* Ws2    = (const float*)d_in[8];
    const float* bs2    = (const float*)d_in[9];
    const int* u2i_src  = (const int*)d_in[10];
    const int* u2i_dst  = (const int*)d_in[11];
    const int* i2u_src  = (const int*)d_in[12];
    const int* i2u_dst  = (const int*)d_in[13];
    const int* pos_u    = (const int*)d_in[14];
    const int* pos_i    = (const int*)d_in[15];
    const int* neg_u    = (const int*)d_in[16];
    const int* neg_i    = (const int*)d_in[17];

    float* out = (float*)d_out;
    float* out_hu = out;                       // [NU,64]
    float* out_hi = out + (size_t)NU * 64;     // [NI,64]
    float* out_pos = out + (size_t)NU * 64 + (size_t)NI * 64;
    float* out_neg = out_pos + NP;

    // workspace layout
    char* ws = (char*)d_ws;
    size_t off = 0;
    auto alloc = [&](size_t bytes) -> void* {
        void* p = ws + off;
        off = (off + bytes + 255) & ~(size_t)255;
        return p;
    };
    float* hu_b = (float*)alloc((size_t)NU * 128 * 4);
    float* hi_b = (float*)alloc((size_t)NI * 128 * 4);
    float* hu_a = (float*)alloc((size_t)NU * 128 * 4);
    float* hi_a = (float*)alloc((size_t)NI * 128 * 4);
    float* agg  = (float*)alloc((size_t)NU * 128 * 4);
    int* csr_u2i = (int*)alloc((size_t)NE * 4);
    int* csr_i2u = (int*)alloc((size_t)NE * 4);
    int* rs_i   = (int*)alloc((size_t)(NI + 1) * 4);
    int* rs_u   = (int*)alloc((size_t)(NU + 1) * 4);
    int* deg    = (int*)alloc((size_t)NU * 4);
    int* cursor = (int*)alloc((size_t)NU * 4);
    int* bsum   = (int*)alloc(1024 * 4);
    (void)ws_size; (void)in_sizes; (void)n_in; (void)out_size;

    const int eblocks = (NE + 255) / 256;

    // ---- CSR for u2i (dst = items) ----
    {
        hipMemsetAsync(deg, 0, (size_t)NI * 4, stream);
        hist_kernel<<<eblocks, 256, 0, stream>>>(u2i_dst, deg, NE);
        int nb = (NI + 1023) / 1024;
        scan_local_kernel<<<nb, 1024, 0, stream>>>(deg, rs_i, bsum, NI);
        scan_bsum_kernel<<<1, 1024, 0, stream>>>(bsum, nb);
        scan_finalize_kernel<<<nb, 1024, 0, stream>>>(rs_i, bsum, cursor, NI, NE);
        fill_kernel<<<eblocks, 256, 0, stream>>>(u2i_src, u2i_dst, cursor, csr_u2i, NE);
    }
    // ---- CSR for i2u (dst = users) ----
    {
        hipMemsetAsync(deg, 0, (size_t)NU * 4, stream);
        hist_kernel<<<eblocks, 256, 0, stream>>>(i2u_dst, deg, NE);
        int nb = (NU + 1023) / 1024;
        scan_local_kernel<<<nb, 1024, 0, stream>>>(deg, rs_u, bsum, NU);
        scan_bsum_kernel<<<1, 1024, 0, stream>>>(bsum, nb);
        scan_finalize_kernel<<<nb, 1024, 0, stream>>>(rs_u, bsum, cursor, NU, NE);
        fill_kernel<<<eblocks, 256, 0, stream>>>(i2u_src, i2u_dst, cursor, csr_i2u, NE);
    }

    const int gi = (NI + 1) / 2, gu = (NU + 1) / 2;          // agg grids
    const int ci = (NI + 31) / 32, cu = (NU + 31) / 32;      // conv grids

    // ---- layer 0 (reads inputs) ----
    agg_kernel<<<gi, 256, 0, stream>>>(h_user, rs_i, csr_u2i, agg, NI);
    conv_kernel<128><<<ci, 256, 0, stream>>>(agg, h_item, Wn01 + 0, bn01 + 0,
                                             Ws01 + 0, bs01 + 0, hi_b, NI);
    agg_kernel<<<gu, 256, 0, stream>>>(h_item, rs_u, csr_i2u, agg, NU);
    conv_kernel<128><<<cu, 256, 0, stream>>>(agg, h_user, Wn01 + 16384, bn01 + 128,
                                             Ws01 + 16384, bs01 + 128, hu_b, NU);
    // ---- layer 1 ----
    agg_kernel<<<gi, 256, 0, stream>>>(hu_b, rs_i, csr_u2i, agg, NI);
    conv_kernel<128><<<ci, 256, 0, stream>>>(agg, hi_b, Wn01 + 32768, bn01 + 256,
                                             Ws01 + 32768, bs01 + 256, hi_a, NI);
    agg_kernel<<<gu, 256, 0, stream>>>(hi_b, rs_u, csr_i2u, agg, NU);
    conv_kernel<128><<<cu, 256, 0, stream>>>(agg, hu_b, Wn01 + 49152, bn01 + 384,
                                             Ws01 + 49152, bs01 + 384, hu_a, NU);
    // ---- layer 2 (writes d_out embeddings) ----
    agg_kernel<<<gi, 256, 0, stream>>>(hu_a, rs_i, csr_u2i, agg, NI);
    conv_kernel<64><<<ci, 256, 0, stream>>>(agg, hi_a, Wn2 + 0, bn2 + 0,
                                            Ws2 + 0, bs2 + 0, out_hi, NI);
    agg_kernel<<<gu, 256, 0, stream>>>(hi_a, rs_u, csr_i2u, agg, NU);
    conv_kernel<64><<<cu, 256, 0, stream>>>(agg, hu_a, Wn2 + 8192, bn2 + 64,
                                            Ws2 + 8192, bs2 + 64, out_hu, NU);

    // ---- cosine scores ----
    const int pblocks = (NP + 15) / 16;
    score_kernel<<<pblocks, 256, 0, stream>>>(out_hu, out_hi, pos_u, pos_i, out_pos, NP);
    score_kernel<<<pblocks, 256, 0, stream>>>(out_hu, out_hi, neg_u, neg_i, out_neg, NP);
}

// Round 4
// 1893.015 us; speedup vs baseline: 1.0035x; 1.0035x over previous
//
#include <hip/hip_runtime.h>
#include <hip/hip_bf16.h>

// Problem constants (from reference)
#define NU 100000
#define NI 50000
#define NE 1000000
#define NP 500000
// D_IN = D_HID = 128, D_OUT = 64

// ---------------- CSR build ----------------

__global__ void hist_kernel(const int* __restrict__ dst, int* __restrict__ deg, int E) {
    int e = blockIdx.x * blockDim.x + threadIdx.x;
    if (e < E) atomicAdd(&deg[dst[e]], 1);
}

__global__ void scan_local_kernel(const int* __restrict__ in, int* __restrict__ out,
                                  int* __restrict__ bsum, int n) {
    __shared__ int s[1024];
    int i = blockIdx.x * 1024 + threadIdx.x;
    int v = (i < n) ? in[i] : 0;
    s[threadIdx.x] = v;
    __syncthreads();
    for (int off = 1; off < 1024; off <<= 1) {
        int t = (threadIdx.x >= off) ? s[threadIdx.x - off] : 0;
        __syncthreads();
        s[threadIdx.x] += t;
        __syncthreads();
    }
    if (i < n) out[i] = s[threadIdx.x] - v;   // exclusive within block
    if (threadIdx.x == 1023) bsum[blockIdx.x] = s[1023];
}

__global__ void scan_bsum_kernel(int* bsum, int nb) {
    __shared__ int s[1024];
    int v = (threadIdx.x < nb) ? bsum[threadIdx.x] : 0;
    s[threadIdx.x] = v;
    __syncthreads();
    for (int off = 1; off < 1024; off <<= 1) {
        int t = (threadIdx.x >= off) ? s[threadIdx.x - off] : 0;
        __syncthreads();
        s[threadIdx.x] += t;
        __syncthreads();
    }
    if (threadIdx.x < nb) bsum[threadIdx.x] = s[threadIdx.x] - v;  // exclusive
}

__global__ void scan_finalize_kernel(int* __restrict__ rs, const int* __restrict__ bsum,
                                     int* __restrict__ cursor, int n, int E) {
    int i = blockIdx.x * 1024 + threadIdx.x;
    if (i < n) {
        int v = rs[i] + bsum[blockIdx.x];
        rs[i] = v;
        cursor[i] = v;
    }
    if (i == 0) rs[n] = E;
}

__global__ void fill_kernel(const int* __restrict__ src, const int* __restrict__ dst,
                            int* cursor, int* __restrict__ csr, int E) {
    int e = blockIdx.x * blockDim.x + threadIdx.x;
    if (e < E) {
        int p = atomicAdd(&cursor[dst[e]], 1);
        csr[p] = src[e];
    }
}

// ---------------- mean aggregation (CSR, atomic-free) ----------------
// 2 dst nodes per 256-thread block; thread j owns feature dim j (128 dims).
__global__ __launch_bounds__(256) void agg_kernel(const float* __restrict__ hsrc,
                                                  const int* __restrict__ rs,
                                                  const int* __restrict__ csr,
                                                  float* __restrict__ out, int T) {
    int t = blockIdx.x * 2 + (threadIdx.x >> 7);
    int j = threadIdx.x & 127;
    if (t >= T) return;
    int e0 = rs[t], e1 = rs[t + 1];
    float acc = 0.f;
    for (int e = e0; e < e1; ++e) {
        int s = csr[e];
        acc += hsrc[(size_t)s * 128 + j];
    }
    float inv = (e1 > e0) ? 1.f / (float)(e1 - e0) : 0.f;
    out[(size_t)t * 128 + j] = acc * inv;
}

// ---------------- conv: z = hn@Wn + bn + hd@Ws + bs; relu; row L2-norm ----------------
// Tile: 32 rows x DOUT cols per 256-thread block. A = [hn | hd] staged in LDS (K=256).
template <int DOUT>
__global__ __launch_bounds__(256) void conv_kernel(const float* __restrict__ hn,
                                                   const float* __restrict__ hd,
                                                   const float* __restrict__ Wn,
                                                   const float* __restrict__ bn,
                                                   const float* __restrict__ Ws,
                                                   const float* __restrict__ bs,
                                                   float* __restrict__ out, int T) {
    constexpr int TM = 32;
    constexpr int GROUP = DOUT / 4;            // threads cooperating on one row set
    constexpr int RPT = (TM * GROUP) / 256;    // rows per thread (4 for 128, 2 for 64)
    __shared__ float A[TM][264];               // 264: 16B-aligned rows, bank-spread

    const int tid = threadIdx.x;
    const int t0 = blockIdx.x * TM;

    // stage [hn | hd] tile: 32 rows x 256 floats = 2048 float4, 8 per thread
    #pragma unroll
    for (int i = 0; i < 8; ++i) {
        int lin = i * 256 + tid;
        int row = lin >> 6;
        int q   = lin & 63;
        int t   = t0 + row;
        float4 v = {0.f, 0.f, 0.f, 0.f};
        if (t < T) {
            v = (q < 32) ? *(const float4*)&hn[(size_t)t * 128 + (q << 2)]
                         : *(const float4*)&hd[(size_t)t * 128 + ((q - 32) << 2)];
        }
        *(float4*)&A[row][q << 2] = v;
    }
    __syncthreads();

    const int cg = tid % GROUP, rg = tid / GROUP;
    const int c0 = cg * 4, r0 = rg * RPT;

    float acc[RPT][4] = {};
    #pragma unroll
    for (int half = 0; half < 2; ++half) {
        const float* __restrict__ W = half ? Ws : Wn;
        const int kb = half * 128;
        for (int k = 0; k < 128; k += 4) {
            float4 w0 = *(const float4*)&W[(size_t)(k + 0) * DOUT + c0];
            float4 w1 = *(const float4*)&W[(size_t)(k + 1) * DOUT + c0];
            float4 w2 = *(const float4*)&W[(size_t)(k + 2) * DOUT + c0];
            float4 w3 = *(const float4*)&W[(size_t)(k + 3) * DOUT + c0];
            #pragma unroll
            for (int r = 0; r < RPT; ++r) {
                float4 a = *(const float4*)&A[r0 + r][kb + k];
                acc[r][0] = fmaf(a.x, w0.x, acc[r][0]);
                acc[r][1] = fmaf(a.x, w0.y, acc[r][1]);
                acc[r][2] = fmaf(a.x, w0.z, acc[r][2]);
                acc[r][3] = fmaf(a.x, w0.w, acc[r][3]);
                acc[r][0] = fmaf(a.y, w1.x, acc[r][0]);
                acc[r][1] = fmaf(a.y, w1.y, acc[r][1]);
                acc[r][2] = fmaf(a.y, w1.z, acc[r][2]);
                acc[r][3] = fmaf(a.y, w1.w, acc[r][3]);
                acc[r][0] = fmaf(a.z, w2.x, acc[r][0]);
                acc[r][1] = fmaf(a.z, w2.y, acc[r][1]);
                acc[r][2] = fmaf(a.z, w2.z, acc[r][2]);
                acc[r][3] = fmaf(a.z, w2.w, acc[r][3]);
                acc[r][0] = fmaf(a.w, w3.x, acc[r][0]);
                acc[r][1] = fmaf(a.w, w3.y, acc[r][1]);
                acc[r][2] = fmaf(a.w, w3.z, acc[r][2]);
                acc[r][3] = fmaf(a.w, w3.w, acc[r][3]);
            }
        }
    }

    float bias[4];
    #pragma unroll
    for (int c = 0; c < 4; ++c) bias[c] = bn[c0 + c] + bs[c0 + c];

    #pragma unroll
    for (int r = 0; r < RPT; ++r) {
        float n2 = 0.f;
        #pragma unroll
        for (int c = 0; c < 4; ++c) {
            float z = fmaxf(acc[r][c] + bias[c], 0.f);
            acc[r][c] = z;
            n2 = fmaf(z, z, n2);
        }
        #pragma unroll
        for (int m = 1; m < GROUP; m <<= 1) n2 += __shfl_xor(n2, m);
        float inv = 1.f / fmaxf(sqrtf(n2), 1e-12f);
        int t = t0 + r0 + r;
        if (t < T) {
            float4 o = {acc[r][0] * inv, acc[r][1] * inv, acc[r][2] * inv, acc[r][3] * inv};
            *(float4*)&out[(size_t)t * DOUT + c0] = o;
        }
    }
}

// ---------------- cosine scores ----------------
// 16 lanes per pair (16 x float4 = 64 dims)
__global__ __launch_bounds__(256) void score_kernel(const float* __restrict__ hu,
                                                    const float* __restrict__ hi,
                                                    const int* __restrict__ pu,
                                                    const int* __restrict__ pi,
                                                    float* __restrict__ out, int P) {
    int g = threadIdx.x >> 4, l = threadIdx.x & 15;
    int p = blockIdx.x * 16 + g;
    if (p >= P) return;
    int u = pu[p], it = pi[p];
    float4 a = *(const float4*)&hu[(size_t)u * 64 + (l << 2)];
    float4 b = *(const float4*)&hi[(size_t)it * 64 + (l << 2)];
    float d  = a.x * b.x + a.y * b.y + a.z * b.z + a.w * b.w;
    float na = a.x * a.x + a.y * a.y + a.z * a.z + a.w * a.w;
    float nb = b.x * b.x + b.y * b.y + b.z * b.z + b.w * b.w;
    #pragma unroll
    for (int m = 1; m < 16; m <<= 1) {
        d  += __shfl_xor(d, m);
        na += __shfl_xor(na, m);
        nb += __shfl_xor(nb, m);
    }
    if (l == 0) out[p] = d / (fmaxf(sqrtf(na), 1e-12f) * fmaxf(sqrtf(nb), 1e-12f));
}

// ---------------- host ----------------

extern "C" void kernel_launch(void* const* d_in, const int* in_sizes, int n_in,
                              void* d_out, int out_size, void* d_ws, size_t ws_size,
                              hipStream_t stream) {
    const float* h_user = (const float*)d_in[0];
    const float* h_item = (const float*)d_in[1];
    const float* Wn01   = (const float*)d_in[2];
    const float* bn01   = (const float*)d_in[3];
    const float* Ws01   = (const float*)d_in[4];
    const float* bs01   = (const float*)d_in[5];
    const float* Wn2    = (const float*)d_in[6];
    const float* bn2    = (const float*)d_in[7];
    const float* Ws2    = (const float*)d_in[8];
    const float* bs2    = (const float*)d_in[9];
    const int* u2i_src  = (const int*)d_in[10];
    const int* u2i_dst  = (const int*)d_in[11];
    const int* i2u_src  = (const int*)d_in[12];
    const int* i2u_dst  = (const int*)d_in[13];
    const int* pos_u    = (const int*)d_in[14];
    const int* pos_i    = (const int*)d_in[15];
    const int* neg_u    = (const int*)d_in[16];
    const int* neg_i    = (const int*)d_in[17];

    float* out = (float*)d_out;
    float* out_hu = out;                       // [NU,64]
    float* out_hi = out + (size_t)NU * 64;     // [NI,64]
    float* out_pos = out + (size_t)NU * 64 + (size_t)NI * 64;
    float* out_neg = out_pos + NP;

    // workspace layout
    char* ws = (char*)d_ws;
    size_t off = 0;
    auto alloc = [&](size_t bytes) -> void* {
        void* p = ws + off;
        off = (off + bytes + 255) & ~(size_t)255;
        return p;
    };
    float* hu_b = (float*)alloc((size_t)NU * 128 * 4);
    float* hi_b = (float*)alloc((size_t)NI * 128 * 4);
    float* hu_a = (float*)alloc((size_t)NU * 128 * 4);
    float* hi_a = (float*)alloc((size_t)NI * 128 * 4);
    float* agg  = (float*)alloc((size_t)NU * 128 * 4);
    int* csr_u2i = (int*)alloc((size_t)NE * 4);
    int* csr_i2u = (int*)alloc((size_t)NE * 4);
    int* rs_i   = (int*)alloc((size_t)(NI + 1) * 4);
    int* rs_u   = (int*)alloc((size_t)(NU + 1) * 4);
    int* deg    = (int*)alloc((size_t)NU * 4);
    int* cursor = (int*)alloc((size_t)NU * 4);
    int* bsum   = (int*)alloc(1024 * 4);
    (void)ws_size; (void)in_sizes; (void)n_in; (void)out_size;

    const int eblocks = (NE + 255) / 256;

    // ---- CSR for u2i (dst = items) ----
    {
        hipMemsetAsync(deg, 0, (size_t)NI * 4, stream);
        hist_kernel<<<eblocks, 256, 0, stream>>>(u2i_dst, deg, NE);
        int nb = (NI + 1023) / 1024;
        scan_local_kernel<<<nb, 1024, 0, stream>>>(deg, rs_i, bsum, NI);
        scan_bsum_kernel<<<1, 1024, 0, stream>>>(bsum, nb);
        scan_finalize_kernel<<<nb, 1024, 0, stream>>>(rs_i, bsum, cursor, NI, NE);
        fill_kernel<<<eblocks, 256, 0, stream>>>(u2i_src, u2i_dst, cursor, csr_u2i, NE);
    }
    // ---- CSR for i2u (dst = users) ----
    {
        hipMemsetAsync(deg, 0, (size_t)NU * 4, stream);
        hist_kernel<<<eblocks, 256, 0, stream>>>(i2u_dst, deg, NE);
        int nb = (NU + 1023) / 1024;
        scan_local_kernel<<<nb, 1024, 0, stream>>>(deg, rs_u, bsum, NU);
        scan_bsum_kernel<<<1, 1024, 0, stream>>>(bsum, nb);
        scan_finalize_kernel<<<nb, 1024, 0, stream>>>(rs_u, bsum, cursor, NU, NE);
        fill_kernel<<<eblocks, 256, 0, stream>>>(i2u_src, i2u_dst, cursor, csr_i2u, NE);
    }

    const int gi = (NI + 1) / 2, gu = (NU + 1) / 2;          // agg grids
    const int ci = (NI + 31) / 32, cu = (NU + 31) / 32;      // conv grids

    // ---- layer 0 (reads inputs) ----
    agg_kernel<<<gi, 256, 0, stream>>>(h_user, rs_i, csr_u2i, agg, NI);
    conv_kernel<128><<<ci, 256, 0, stream>>>(agg, h_item, Wn01 + 0, bn01 + 0,
                                             Ws01 + 0, bs01 + 0, hi_b, NI);
    agg_kernel<<<gu, 256, 0, stream>>>(h_item, rs_u, csr_i2u, agg, NU);
    conv_kernel<128><<<cu, 256, 0, stream>>>(agg, h_user, Wn01 + 16384, bn01 + 128,
                                             Ws01 + 16384, bs01 + 128, hu_b, NU);
    // ---- layer 1 ----
    agg_kernel<<<gi, 256, 0, stream>>>(hu_b, rs_i, csr_u2i, agg, NI);
    conv_kernel<128><<<ci, 256, 0, stream>>>(agg, hi_b, Wn01 + 32768, bn01 + 256,
                                             Ws01 + 32768, bs01 + 256, hi_a, NI);
    agg_kernel<<<gu, 256, 0, stream>>>(hi_b, rs_u, csr_i2u, agg, NU);
    conv_kernel<128><<<cu, 256, 0, stream>>>(agg, hu_b, Wn01 + 49152, bn01 + 384,
                                             Ws01 + 49152, bs01 + 384, hu_a, NU);
    // ---- layer 2 (writes d_out embeddings) ----
    agg_kernel<<<gi, 256, 0, stream>>>(hu_a, rs_i, csr_u2i, agg, NI);
    conv_kernel<64><<<ci, 256, 0, stream>>>(agg, hi_a, Wn2 + 0, bn2 + 0,
                                            Ws2 + 0, bs2 + 0, out_hi, NI);
    agg_kernel<<<gu, 256, 0, stream>>>(hi_a, rs_u, csr_i2u, agg, NU);
    conv_kernel<64><<<cu, 256, 0, stream>>>(agg, hu_a, Wn2 + 8192, bn2 + 64,
                                            Ws2 + 8192, bs2 + 64, out_hu, NU);

    // ---- cosine scores ----
    const int pblocks = (NP + 15) / 16;
    score_kernel<<<pblocks, 256, 0, stream>>>(out_hu, out_hi, pos_u, pos_i, out_pos, NP);
    score_kernel<<<pblocks, 256, 0, stream>>>(out_hu, out_hi, neg_u, neg_i, out_neg, NP);
}